// Round 6
// baseline (277.799 us; speedup 1.0000x reference)
//
#include <hip/hip_runtime.h>

#define D 128
#define NB 32              // histogram/scatter blocks per type
#define RBITS 15           // node-range split: 32768 bins per range
#define RSIZE (1 << RBITS)
#define RWORDS (RSIZE / 2) // 16384 packed words = 64 KB LDS

typedef short short8 __attribute__((ext_vector_type(8)));
typedef float f32x4 __attribute__((ext_vector_type(4)));

static __device__ __forceinline__ unsigned short f2bf(float f) {
    unsigned int u = __float_as_uint(f);
    unsigned int r = (u + 0x7FFFu + ((u >> 16) & 1u)) >> 16;
    return (unsigned short)r;
}
static __device__ __forceinline__ unsigned int pk2bf(float lo, float hi) {
    return (unsigned int)f2bf(lo) | ((unsigned int)f2bf(hi) << 16);
}

// ---------------- K1: per-block packed histograms (LDS atomics only) ----------------
__global__ __launch_bounds__(1024) void k_hist(const int* __restrict__ src,
                                               const int* __restrict__ dst,
                                               unsigned int* __restrict__ hist,
                                               int E, int NW) {
    __shared__ unsigned int h[RWORDS];
    int t = threadIdx.x;
    int b = blockIdx.x;
    int type = blockIdx.y;
    int z = blockIdx.z;
    const int* __restrict__ ids = type ? dst : src;
    for (int i = t; i < RWORDS; i += 1024) h[i] = 0;
    __syncthreads();
    int slice = (E + NB - 1) / NB;
    int beg = b * slice;
    int end = beg + slice; if (end > E) end = E;
    for (int e = beg + t; e < end; e += 1024) {
        int v = ids[e];
        if ((v >> RBITS) != z) continue;
        int lv = v & (RSIZE - 1);
        atomicAdd(&h[lv >> 1], 1u << ((lv & 1) * 16));
    }
    __syncthreads();
    unsigned int* out = hist + (size_t)(type * NB + b) * NW;
    int wbeg = z * RWORDS;
    int wend = wbeg + RWORDS; if (wend > NW) wend = NW;
    for (int i = wbeg + t; i < wend; i += 1024) out[i] = h[i - wbeg];
}

// ---------------- K2: reduce hists -> deg/norms; rewrite src-hist as dst prefixes;
//                     also emit per-block partial sums (fused scan phase 1) ----------------
__global__ __launch_bounds__(256) void k_hreduce(unsigned int* __restrict__ hist,
                                                 int* __restrict__ deg_in,
                                                 float* __restrict__ norm_out,
                                                 float* __restrict__ norm_in,
                                                 int* __restrict__ partial,
                                                 int N, int NW) {
    __shared__ int red[256];
    int t = threadIdx.x;
    int w = blockIdx.x * 256 + t;
    unsigned int p0 = 0, p1 = 0;
    if (w < NW) {
        unsigned int do0 = 0, do1 = 0;
        for (int b = 0; b < NB; b++) {
            unsigned int v = hist[(size_t)b * NW + w];
            do0 += v & 0xffffu; do1 += v >> 16;
        }
        for (int b = 0; b < NB; b++) {
            unsigned int v = hist[(size_t)(NB + b) * NW + w];
            hist[(size_t)b * NW + w] = p0 | (p1 << 16);  // thread-exclusive word: no race
            p0 += v & 0xffffu; p1 += v >> 16;
        }
        int n0 = 2 * w, n1 = 2 * w + 1;
        deg_in[n0]   = (int)p0;
        norm_out[n0] = rsqrtf((float)(do0 > 1 ? do0 : 1));
        norm_in[n0]  = rsqrtf((float)(p0 > 1 ? p0 : 1));
        if (n1 < N) {
            deg_in[n1]   = (int)p1;
            norm_out[n1] = rsqrtf((float)(do1 > 1 ? do1 : 1));
            norm_in[n1]  = rsqrtf((float)(p1 > 1 ? p1 : 1));
        } else {
            p1 = 0;
        }
    }
    red[t] = (int)(p0 + p1);
    __syncthreads();
    for (int off = 128; off > 0; off >>= 1) {
        if (t < off) red[t] += red[t + off];
        __syncthreads();
    }
    if (t == 0) partial[blockIdx.x] = red[0];
}

__global__ void k_scan2(int* __restrict__ partial, int* __restrict__ offsets, int nb, int N) {
    if (threadIdx.x == 0) {
        int run = 0;
        for (int i = 0; i < nb; i++) { int v = partial[i]; partial[i] = run; run += v; }
        offsets[N] = run;
    }
}

// 512 nodes per block (matches k_hreduce partition)
__global__ __launch_bounds__(256) void k_scan3(const int* __restrict__ deg,
                                               const int* __restrict__ partial,
                                               int* __restrict__ offsets, int N) {
    __shared__ int red[256];
    int t = threadIdx.x;
    int base = blockIdx.x * 512 + t * 2;
    int v0 = (base < N) ? deg[base] : 0;
    int v1 = (base + 1 < N) ? deg[base + 1] : 0;
    int s = v0 + v1;
    red[t] = s;
    __syncthreads();
    for (int off = 1; off < 256; off <<= 1) {
        int a = (t >= off) ? red[t - off] : 0;
        __syncthreads();
        red[t] += a;
        __syncthreads();
    }
    int excl = red[t] - s + partial[blockIdx.x];
    if (base < N)     offsets[base] = excl;
    if (base + 1 < N) offsets[base + 1] = excl + v0;
}

// ---------------- K4: counting-sort scatter — no global atomics ----------------
__global__ __launch_bounds__(1024) void k_scatter(const int* __restrict__ src,
                                                  const int* __restrict__ dst,
                                                  const int* __restrict__ offsets,
                                                  const unsigned int* __restrict__ prefix,
                                                  int* __restrict__ edge_src,
                                                  int E, int NW) {
    __shared__ unsigned int h[RWORDS];
    int t = threadIdx.x;
    int b = blockIdx.x;
    int z = blockIdx.y;
    for (int i = t; i < RWORDS; i += 1024) h[i] = 0;
    __syncthreads();
    int slice = (E + NB - 1) / NB;
    int beg = b * slice;
    int end = beg + slice; if (end > E) end = E;
    const unsigned int* __restrict__ prow = prefix + (size_t)b * NW;
    for (int e = beg + t; e < end; e += 1024) {
        int d = dst[e];
        if ((d >> RBITS) != z) continue;
        int lv = d & (RSIZE - 1);
        int sh = (lv & 1) * 16;
        unsigned int old = atomicAdd(&h[lv >> 1], 1u << sh);
        int rank = (int)((old >> sh) & 0xffffu);
        int base = offsets[d] + (int)((prow[d >> 1] >> sh) & 0xffffu);
        edge_src[base + rank] = src[e];
    }
}

// ---------------- x -> bf16 (xh) and bf16 pre-scaled by norm_out (xsh) ----------------
__global__ __launch_bounds__(256) void k_x2bf(const float* __restrict__ x,
                                              const float* __restrict__ norm_out,
                                              unsigned short* __restrict__ xh,
                                              unsigned short* __restrict__ xsh,
                                              long long total4) {
    long long i = (long long)blockIdx.x * blockDim.x + threadIdx.x;
    if (i >= total4) return;
    int row = (int)(i >> 5);   // 32 float4 per 128-wide row
    float ns = norm_out[row];
    float4 v = *(const float4*)&x[i * 4];
    ushort4 o;
    o.x = f2bf(v.x); o.y = f2bf(v.y); o.z = f2bf(v.z); o.w = f2bf(v.w);
    *(ushort4*)&xh[i * 4] = o;
    ushort4 os;
    os.x = f2bf(v.x * ns); os.y = f2bf(v.y * ns); os.z = f2bf(v.z * ns); os.w = f2bf(v.w * ns);
    *(ushort4*)&xsh[i * 4] = os;
}

// ---------------- fold W_conv into W_aggr; bf16 transposed Wt[n][k] ----------------
__global__ void k_wcomb(const float* __restrict__ Wc, const float* __restrict__ Wa,
                        const float* __restrict__ bc, const float* __restrict__ ba,
                        unsigned short* __restrict__ Wt, float* __restrict__ beff) {
    int b = blockIdx.x;   // k index 0..255, or 256 for bias
    int j = threadIdx.x;  // n index, 128 threads
    if (b < 128) {
        float acc = 0.f;
        for (int k = 0; k < 128; k++) acc += Wc[b * 128 + k] * Wa[k * 128 + j];
        Wt[(size_t)j * 256 + b] = f2bf(acc);
    } else if (b < 256) {
        Wt[(size_t)j * 256 + b] = f2bf(Wa[b * 128 + j]);
    } else {
        float acc = ba[j];
        for (int k = 0; k < 128; k++) acc += bc[k] * Wa[k * 128 + j];
        beff[j] = acc;
    }
}

// ---------------- FUSED: aggregate (CSR gather) + MFMA GEMM ----------------
// out = [agg(xsh)*norm_in | xh] @ W + beff.  Block: 256 thr, tile 64 rows x 128 cols.
// Strides 132 bf16 = 66 words, gcd(66,32)=2 -> 2-way LDS aliasing (free).
#define ASTR 132
#define BSTR 132
__global__ __launch_bounds__(256) void k_fused(const unsigned short* __restrict__ xsh,
                                               const unsigned short* __restrict__ xh,
                                               const int* __restrict__ edge_src,
                                               const int* __restrict__ offsets,
                                               const float* __restrict__ norm_in,
                                               const unsigned short* __restrict__ Wt,
                                               const float* __restrict__ beff,
                                               float* __restrict__ out, int N) {
    __shared__ unsigned short Bs[128 * BSTR];  // 33.8 KB
    __shared__ unsigned short As[64 * ASTR];   // 16.9 KB

    int t = threadIdx.x;
    int w = t >> 6;
    int lane = t & 63;
    int m = lane & 15;     // li for gather, A-row / C-col for MFMA
    int q = lane >> 4;     // group for gather, k-quad for MFMA
    int row0 = blockIdx.x * 64;

    // stage Bs for kh=0 (Wt k-cols 0..127)
#pragma unroll
    for (int i = 0; i < 8; i++) {
        int idx = t + i * 256;
        int rr = idx >> 4;
        int cc = (idx & 15) * 8;
        *(short8*)&Bs[rr * BSTR + cc] = *(const short8*)&Wt[(size_t)rr * 256 + cc];
    }

    // phase A: each wave aggregates its 16 A-rows into As (bf16)
    for (int i = 0; i < 16; i++) {
        int node = row0 + w * 16 + i;
        float acc[8];
#pragma unroll
        for (int j = 0; j < 8; j++) acc[j] = 0.f;
        if (node < N) {
            int beg = offsets[node];
            int end = offsets[node + 1];
            for (int jb = beg; jb < end; jb += 64) {
                int cnt = end - jb; if (cnt > 64) cnt = 64;
                int eidx = (lane < cnt) ? edge_src[jb + lane] : 0;  // coalesced batch
#pragma unroll 4
                for (int k = 0; k < cnt; k += 4) {
                    int kg = k + q;
                    int s = __shfl(eidx, kg);
                    if (kg < cnt) {
                        uint4 raw = *(const uint4*)&xsh[(size_t)s * D + m * 8];
                        acc[0] += __uint_as_float(raw.x << 16);
                        acc[1] += __uint_as_float(raw.x & 0xffff0000u);
                        acc[2] += __uint_as_float(raw.y << 16);
                        acc[3] += __uint_as_float(raw.y & 0xffff0000u);
                        acc[4] += __uint_as_float(raw.z << 16);
                        acc[5] += __uint_as_float(raw.z & 0xffff0000u);
                        acc[6] += __uint_as_float(raw.w << 16);
                        acc[7] += __uint_as_float(raw.w & 0xffff0000u);
                    }
                }
            }
        }
#pragma unroll
        for (int j = 0; j < 8; j++) {
            acc[j] += __shfl_xor(acc[j], 16);
            acc[j] += __shfl_xor(acc[j], 32);
        }
        if (q == 0) {
            float nd = (node < N) ? norm_in[node] : 0.f;
            uint4 o;
            o.x = pk2bf(acc[0] * nd, acc[1] * nd);
            o.y = pk2bf(acc[2] * nd, acc[3] * nd);
            o.z = pk2bf(acc[4] * nd, acc[5] * nd);
            o.w = pk2bf(acc[6] * nd, acc[7] * nd);
            *(uint4*)&As[(w * 16 + i) * ASTR + m * 8] = o;
        }
    }
    __syncthreads();

    f32x4 cacc[8];
#pragma unroll
    for (int ct = 0; ct < 8; ct++) cacc[ct] = (f32x4){0.f, 0.f, 0.f, 0.f};

    // kh=0: A fragments from LDS As
    int arow_l = w * 16 + m;
#pragma unroll
    for (int kk = 0; kk < 4; kk++) {
        short8 a = *(short8*)&As[arow_l * ASTR + kk * 32 + q * 8];
#pragma unroll
        for (int ct = 0; ct < 8; ct++) {
            short8 b = *(short8*)&Bs[(ct * 16 + m) * BSTR + kk * 32 + q * 8];
            cacc[ct] = __builtin_amdgcn_mfma_f32_16x16x32_bf16(a, b, cacc[ct], 0, 0, 0);
        }
    }
    __syncthreads();

    // restage Bs for kh=1 (Wt k-cols 128..255)
#pragma unroll
    for (int i = 0; i < 8; i++) {
        int idx = t + i * 256;
        int rr = idx >> 4;
        int cc = (idx & 15) * 8;
        *(short8*)&Bs[rr * BSTR + cc] = *(const short8*)&Wt[(size_t)rr * 256 + 128 + cc];
    }
    __syncthreads();

    // kh=1: A fragments from xh (skip connection)
    int arow = row0 + w * 16 + m;
    bool arow_ok = arow < N;
    const unsigned short* arowp = xh + (size_t)arow * D;
#pragma unroll
    for (int kk = 0; kk < 4; kk++) {
        short8 a = (short8){0,0,0,0,0,0,0,0};
        if (arow_ok) a = *(const short8*)&arowp[kk * 32 + q * 8];
#pragma unroll
        for (int ct = 0; ct < 8; ct++) {
            short8 b = *(short8*)&Bs[(ct * 16 + m) * BSTR + kk * 32 + q * 8];
            cacc[ct] = __builtin_amdgcn_mfma_f32_16x16x32_bf16(a, b, cacc[ct], 0, 0, 0);
        }
    }

    // epilogue: C layout col=m, row=q*4+j
#pragma unroll
    for (int ct = 0; ct < 8; ct++) {
        int col = ct * 16 + m;
        float bv = beff[col];
#pragma unroll
        for (int j = 0; j < 4; j++) {
            int r = row0 + w * 16 + q * 4 + j;
            if (r < N) out[(size_t)r * D + col] = cacc[ct][j] + bv;
        }
    }
}

static size_t align256(size_t v) { return (v + 255) & ~(size_t)255; }

extern "C" void kernel_launch(void* const* d_in, const int* in_sizes, int n_in,
                              void* d_out, int out_size, void* d_ws, size_t ws_size,
                              hipStream_t stream) {
    const float* x     = (const float*)d_in[0];
    const int*   src   = (const int*)d_in[1];
    const int*   dst   = (const int*)d_in[2];
    const float* Wconv = (const float*)d_in[3];
    const float* bconv = (const float*)d_in[4];
    const float* Waggr = (const float*)d_in[5];
    const float* baggr = (const float*)d_in[6];
    float* out = (float*)d_out;

    int N = in_sizes[0] / D;
    int E = in_sizes[1];
    int NW = (N + 1) / 2;               // packed words per histogram row
    int RS = (N + RSIZE - 1) / RSIZE;   // node-range splits
    int nbh = (NW + 255) / 256;         // hreduce/scan blocks (512 nodes each)

    char* p = (char*)d_ws;
    // hist: [src half: NB rows][dst half: NB rows]; after k_hreduce the src half
    // holds per-block dst prefixes and the dst half is dead -> edge_src overlays it.
    unsigned int* hist = (unsigned int*)p;
    int* edge_src = (int*)(hist + (size_t)NB * NW);
    size_t dstHalf = (size_t)NB * NW * 4;
    size_t edgeBytes = (size_t)E * 4;
    p += align256((size_t)NB * NW * 4 + (edgeBytes > dstHalf ? edgeBytes : dstHalf));
    int* deg_in  = (int*)p;      p += align256((size_t)N * sizeof(int));
    int* offsets = (int*)p;      p += align256((size_t)(N + 1) * sizeof(int));
    int* partial = (int*)p;      p += align256((size_t)(nbh + 1) * sizeof(int));
    float* norm_out = (float*)p; p += align256((size_t)N * sizeof(float));
    float* norm_in  = (float*)p; p += align256((size_t)N * sizeof(float));
    float* beff  = (float*)p;    p += align256(128 * sizeof(float));
    unsigned short* xh  = (unsigned short*)p; p += align256((size_t)N * D * 2);
    unsigned short* xsh = (unsigned short*)p; p += align256((size_t)N * D * 2);
    unsigned short* Wt  = (unsigned short*)p; p += align256(256 * 128 * 2);

    k_hist<<<dim3(NB, 2, RS), 1024, 0, stream>>>(src, dst, hist, E, NW);
    k_hreduce<<<nbh, 256, 0, stream>>>(hist, deg_in, norm_out, norm_in, partial, N, NW);
    k_scan2<<<1, 64, 0, stream>>>(partial, offsets, nbh, N);
    k_scan3<<<nbh, 256, 0, stream>>>(deg_in, partial, offsets, N);
    k_scatter<<<dim3(NB, RS), 1024, 0, stream>>>(src, dst, offsets, hist, edge_src, E, NW);

    long long total4 = (long long)N * D / 4;
    k_x2bf<<<(int)((total4 + 255) / 256), 256, 0, stream>>>(x, norm_out, xh, xsh, total4);
    k_wcomb<<<257, 128, 0, stream>>>(Wconv, Waggr, bconv, baggr, Wt, beff);
    k_fused<<<(N + 63) / 64, 256, 0, stream>>>(xsh, xh, edge_src, offsets, norm_in, Wt, beff, out, N);
}

// Round 7
// 203.321 us; speedup vs baseline: 1.3663x; 1.3663x over previous
//
#include <hip/hip_runtime.h>

#define D 128
#define NB 32              // histogram/scatter blocks per type
#define RBITS 15           // node-range split: 32768 bins per range
#define RSIZE (1 << RBITS)
#define RWORDS (RSIZE / 2) // 16384 packed words = 64 KB LDS

typedef short short8 __attribute__((ext_vector_type(8)));
typedef float f32x4 __attribute__((ext_vector_type(4)));

static __device__ __forceinline__ unsigned short f2bf(float f) {
    unsigned int u = __float_as_uint(f);
    unsigned int r = (u + 0x7FFFu + ((u >> 16) & 1u)) >> 16;
    return (unsigned short)r;
}
static __device__ __forceinline__ float bflo(unsigned int w) {
    return __uint_as_float(w << 16);
}
static __device__ __forceinline__ float bfhi(unsigned int w) {
    return __uint_as_float(w & 0xffff0000u);
}
static __device__ __forceinline__ unsigned int pk2bf(float lo, float hi) {
    return (unsigned int)f2bf(lo) | ((unsigned int)f2bf(hi) << 16);
}

// ---------------- S1: fused front-end: zone A = histograms, zone B = x->bf16,
//                     zone C = weight fold. All independent of each other. ----------------
__global__ __launch_bounds__(1024) void k_stage1(
    const int* __restrict__ src, const int* __restrict__ dst,
    unsigned int* __restrict__ hist, int E, int NW, int nHist,
    const float* __restrict__ x, unsigned short* __restrict__ xh, long long total4, int nX4,
    const float* __restrict__ Wc, const float* __restrict__ Wa,
    const float* __restrict__ bc, const float* __restrict__ ba,
    unsigned short* __restrict__ Wt, float* __restrict__ beff) {
    __shared__ unsigned int h[RWORDS];
    int t = threadIdx.x;
    int bx = blockIdx.x;

    if (bx < nHist) {
        // ---- zone A: per-block packed histograms (LDS atomics only) ----
        int b = bx % NB;
        int type = (bx / NB) & 1;
        int z = bx / (NB * 2);
        const int* __restrict__ ids = type ? dst : src;
        for (int i = t; i < RWORDS; i += 1024) h[i] = 0;
        __syncthreads();
        int slice = (E + NB - 1) / NB;
        int beg = b * slice;
        int end = beg + slice; if (end > E) end = E;
        for (int e = beg + t; e < end; e += 1024) {
            int v = ids[e];
            if ((v >> RBITS) != z) continue;
            int lv = v & (RSIZE - 1);
            atomicAdd(&h[lv >> 1], 1u << ((lv & 1) * 16));
        }
        __syncthreads();
        unsigned int* outp = hist + (size_t)(type * NB + b) * NW;
        int wbeg = z * RWORDS;
        int wend = wbeg + RWORDS; if (wend > NW) wend = NW;
        for (int i = wbeg + t; i < wend; i += 1024) outp[i] = h[i - wbeg];
    } else if (bx < nHist + nX4) {
        // ---- zone B: x -> bf16 (unscaled) ----
        long long i = (long long)(bx - nHist) * 1024 + t;
        if (i < total4) {
            float4 v = *(const float4*)&x[i * 4];
            ushort4 o;
            o.x = f2bf(v.x); o.y = f2bf(v.y); o.z = f2bf(v.z); o.w = f2bf(v.w);
            *(ushort4*)&xh[i * 4] = o;
        }
    } else {
        // ---- zone C: Wt[j*256+k] = k<128 ? (Wc@Wa_top)[k][j] : Wa[k][j]; beff ----
        int cidx = bx - nHist - nX4;
        if (cidx < 32) {
            int o = cidx * 1024 + t;
            int k = o >> 7;
            int j = o & 127;
            float acc;
            if (k < 128) {
                acc = 0.f;
                for (int l = 0; l < 128; l++) acc += Wc[k * 128 + l] * Wa[l * 128 + j];
            } else {
                acc = Wa[k * 128 + j];
            }
            Wt[(size_t)j * 256 + k] = f2bf(acc);
        } else if (t < 128) {
            float acc = ba[t];
            for (int k = 0; k < 128; k++) acc += bc[k] * Wa[k * 128 + t];
            beff[t] = acc;
        }
    }
}

// ---------------- S2: reduce hists -> deg/norms; rewrite src-hist as dst prefixes;
//                     emit per-block partial sums ----------------
__global__ __launch_bounds__(256) void k_hreduce(unsigned int* __restrict__ hist,
                                                 int* __restrict__ deg_in,
                                                 float* __restrict__ norm_out,
                                                 float* __restrict__ norm_in,
                                                 int* __restrict__ partial,
                                                 int N, int NW) {
    __shared__ int red[256];
    int t = threadIdx.x;
    int w = blockIdx.x * 256 + t;
    unsigned int p0 = 0, p1 = 0;
    if (w < NW) {
        unsigned int do0 = 0, do1 = 0;
        for (int b = 0; b < NB; b++) {
            unsigned int v = hist[(size_t)b * NW + w];
            do0 += v & 0xffffu; do1 += v >> 16;
        }
        for (int b = 0; b < NB; b++) {
            unsigned int v = hist[(size_t)(NB + b) * NW + w];
            hist[(size_t)b * NW + w] = p0 | (p1 << 16);  // thread-exclusive word: no race
            p0 += v & 0xffffu; p1 += v >> 16;
        }
        int n0 = 2 * w, n1 = 2 * w + 1;
        deg_in[n0]   = (int)p0;
        norm_out[n0] = rsqrtf((float)(do0 > 1 ? do0 : 1));
        norm_in[n0]  = rsqrtf((float)(p0 > 1 ? p0 : 1));
        if (n1 < N) {
            deg_in[n1]   = (int)p1;
            norm_out[n1] = rsqrtf((float)(do1 > 1 ? do1 : 1));
            norm_in[n1]  = rsqrtf((float)(p1 > 1 ? p1 : 1));
        } else {
            p1 = 0;
        }
    }
    red[t] = (int)(p0 + p1);
    __syncthreads();
    for (int off = 128; off > 0; off >>= 1) {
        if (t < off) red[t] += red[t + off];
        __syncthreads();
    }
    if (t == 0) partial[blockIdx.x] = red[0];
}

// ---------------- S3: scan with self-computed block prefix (512 nodes/block) ----------------
__global__ __launch_bounds__(256) void k_scan3(const int* __restrict__ deg,
                                               const int* __restrict__ partial,
                                               int* __restrict__ offsets, int N) {
    __shared__ int red[256];
    int t = threadIdx.x;
    int bx = blockIdx.x;
    // block prefix over partials (gridDim.x <= 256)
    int pv = (t < bx) ? partial[t] : 0;
    red[t] = pv;
    __syncthreads();
    for (int off = 128; off > 0; off >>= 1) {
        if (t < off) red[t] += red[t + off];
        __syncthreads();
    }
    int base = red[0];
    __syncthreads();

    int nb2 = bx * 512 + t * 2;
    int v0 = (nb2 < N) ? deg[nb2] : 0;
    int v1 = (nb2 + 1 < N) ? deg[nb2 + 1] : 0;
    int s = v0 + v1;
    red[t] = s;
    __syncthreads();
    for (int off = 1; off < 256; off <<= 1) {
        int a = (t >= off) ? red[t - off] : 0;
        __syncthreads();
        red[t] += a;
        __syncthreads();
    }
    int excl = red[t] - s + base;
    if (nb2 < N)     offsets[nb2] = excl;
    if (nb2 + 1 < N) offsets[nb2 + 1] = excl + v0;
    if (bx == gridDim.x - 1 && t == 255) offsets[N] = base + red[255];
}

// ---------------- S4: counting-sort scatter — no global atomics ----------------
__global__ __launch_bounds__(1024) void k_scatter(const int* __restrict__ src,
                                                  const int* __restrict__ dst,
                                                  const int* __restrict__ offsets,
                                                  const unsigned int* __restrict__ prefix,
                                                  int* __restrict__ edge_src,
                                                  int E, int NW) {
    __shared__ unsigned int h[RWORDS];
    int t = threadIdx.x;
    int b = blockIdx.x;
    int z = blockIdx.y;
    for (int i = t; i < RWORDS; i += 1024) h[i] = 0;
    __syncthreads();
    int slice = (E + NB - 1) / NB;
    int beg = b * slice;
    int end = beg + slice; if (end > E) end = E;
    const unsigned int* __restrict__ prow = prefix + (size_t)b * NW;
    for (int e = beg + t; e < end; e += 1024) {
        int d = dst[e];
        if ((d >> RBITS) != z) continue;
        int lv = d & (RSIZE - 1);
        int sh = (lv & 1) * 16;
        unsigned int old = atomicAdd(&h[lv >> 1], 1u << sh);
        int rank = (int)((old >> sh) & 0xffffu);
        int base = offsets[d] + (int)((prow[d >> 1] >> sh) & 0xffffu);
        edge_src[base + rank] = src[e];
    }
}

// ---------------- S5: CSR aggregation: 8 rows in flight per wave ----------------
// wave = 8 groups x 8 lanes; group g gathers edge (k+g)'s row, 2x16B per lane.
__global__ __launch_bounds__(256) void k_aggr(const unsigned short* __restrict__ xh,
                                              const int* __restrict__ edge_src,
                                              const int* __restrict__ offsets,
                                              const float* __restrict__ norm_out,
                                              const float* __restrict__ norm_in,
                                              unsigned short* __restrict__ yh, int N) {
    int node = blockIdx.x * 4 + (threadIdx.x >> 6);
    int lane = threadIdx.x & 63;
    if (node >= N) return;
    int g = lane >> 3;
    int li = lane & 7;
    int beg = offsets[node];
    int end = offsets[node + 1];

    float acc[16];
#pragma unroll
    for (int i = 0; i < 16; i++) acc[i] = 0.f;

    for (int jb = beg; jb < end; jb += 64) {
        int cnt = end - jb; if (cnt > 64) cnt = 64;
        int eidx = 0; float nsv = 0.f;
        if (lane < cnt) {
            eidx = edge_src[jb + lane];     // coalesced batch
            nsv  = norm_out[eidx];          // batched gather, 64 in flight
        }
        for (int k = 0; k < cnt; k += 8) {
            int kg = k + g;
            int s = __shfl(eidx, kg);
            float ns = __shfl(nsv, kg);
            if (kg < cnt) {
                const uint4* pr = (const uint4*)&xh[(size_t)s * D + li * 16];
                uint4 r0 = pr[0];
                uint4 r1 = pr[1];
                acc[0]  += bflo(r0.x) * ns; acc[1]  += bfhi(r0.x) * ns;
                acc[2]  += bflo(r0.y) * ns; acc[3]  += bfhi(r0.y) * ns;
                acc[4]  += bflo(r0.z) * ns; acc[5]  += bfhi(r0.z) * ns;
                acc[6]  += bflo(r0.w) * ns; acc[7]  += bfhi(r0.w) * ns;
                acc[8]  += bflo(r1.x) * ns; acc[9]  += bfhi(r1.x) * ns;
                acc[10] += bflo(r1.y) * ns; acc[11] += bfhi(r1.y) * ns;
                acc[12] += bflo(r1.z) * ns; acc[13] += bfhi(r1.z) * ns;
                acc[14] += bflo(r1.w) * ns; acc[15] += bfhi(r1.w) * ns;
            }
        }
    }

    // combine the 8 groups (butterfly over lane bits 3,4,5)
#pragma unroll
    for (int i = 0; i < 16; i++) {
        acc[i] += __shfl_xor(acc[i], 8);
        acc[i] += __shfl_xor(acc[i], 16);
        acc[i] += __shfl_xor(acc[i], 32);
    }

    if (g == 0) {
        float nd = norm_in[node];
        uint4 o0, o1;
        o0.x = pk2bf(acc[0] * nd,  acc[1] * nd);
        o0.y = pk2bf(acc[2] * nd,  acc[3] * nd);
        o0.z = pk2bf(acc[4] * nd,  acc[5] * nd);
        o0.w = pk2bf(acc[6] * nd,  acc[7] * nd);
        o1.x = pk2bf(acc[8] * nd,  acc[9] * nd);
        o1.y = pk2bf(acc[10] * nd, acc[11] * nd);
        o1.z = pk2bf(acc[12] * nd, acc[13] * nd);
        o1.w = pk2bf(acc[14] * nd, acc[15] * nd);
        uint4* po = (uint4*)&yh[(size_t)node * D + li * 16];
        po[0] = o0;
        po[1] = o1;
    }
}

// ---------------- S6: MFMA GEMM: out = [yh | xh] @ W + beff ----------------
#define WT_STRIDE 136
__global__ __launch_bounds__(256) void k_gemm(const unsigned short* __restrict__ yh,
                                              const unsigned short* __restrict__ xh,
                                              const unsigned short* __restrict__ Wt,
                                              const float* __restrict__ beff,
                                              float* __restrict__ out, int N) {
    __shared__ unsigned short Bs[128 * WT_STRIDE];

    int t = threadIdx.x;
    int w = t >> 6;
    int lane = t & 63;
    int m = lane & 15;
    int q = lane >> 4;
    int row0 = blockIdx.x * 64;
    int arow = row0 + w * 16 + m;
    bool arow_ok = arow < N;

    f32x4 acc[8];
#pragma unroll
    for (int ct = 0; ct < 8; ct++) acc[ct] = (f32x4){0.f, 0.f, 0.f, 0.f};

    for (int kh = 0; kh < 2; kh++) {
#pragma unroll
        for (int i = 0; i < 8; i++) {
            int idx = t + i * 256;
            int rr = idx >> 4;
            int cc = (idx & 15) * 8;
            *(short8*)&Bs[rr * WT_STRIDE + cc] =
                *(const short8*)&Wt[(size_t)rr * 256 + kh * 128 + cc];
        }
        __syncthreads();

        const unsigned short* Abase = (kh == 0) ? yh : xh;
        const unsigned short* arowp = Abase + (size_t)arow * D;

#pragma unroll
        for (int kk = 0; kk < 4; kk++) {
            short8 a = (short8){0,0,0,0,0,0,0,0};
            if (arow_ok) a = *(const short8*)&arowp[kk * 32 + q * 8];
#pragma unroll
            for (int ct = 0; ct < 8; ct++) {
                short8 b = *(const short8*)&Bs[(ct * 16 + m) * WT_STRIDE + kk * 32 + q * 8];
                acc[ct] = __builtin_amdgcn_mfma_f32_16x16x32_bf16(a, b, acc[ct], 0, 0, 0);
            }
        }
        __syncthreads();
    }

#pragma unroll
    for (int ct = 0; ct < 8; ct++) {
        int col = ct * 16 + m;
        float bv = beff[col];
#pragma unroll
        for (int j = 0; j < 4; j++) {
            int r = row0 + w * 16 + q * 4 + j;
            if (r < N) out[(size_t)r * D + col] = acc[ct][j] + bv;
        }
    }
}

static size_t align256(size_t v) { return (v + 255) & ~(size_t)255; }

extern "C" void kernel_launch(void* const* d_in, const int* in_sizes, int n_in,
                              void* d_out, int out_size, void* d_ws, size_t ws_size,
                              hipStream_t stream) {
    const float* x     = (const float*)d_in[0];
    const int*   src   = (const int*)d_in[1];
    const int*   dst   = (const int*)d_in[2];
    const float* Wconv = (const float*)d_in[3];
    const float* bconv = (const float*)d_in[4];
    const float* Waggr = (const float*)d_in[5];
    const float* baggr = (const float*)d_in[6];
    float* out = (float*)d_out;

    int N = in_sizes[0] / D;
    int E = in_sizes[1];
    int NW = (N + 1) / 2;               // packed words per histogram row
    int RS = (N + RSIZE - 1) / RSIZE;   // node-range splits
    int nbh = (NW + 255) / 256;         // hreduce/scan blocks (512 nodes each)
    int nHist = NB * 2 * RS;
    long long total4 = (long long)N * D / 4;
    int nX4 = (int)((total4 + 1023) / 1024);

    char* p = (char*)d_ws;
    // hist: [src half: NB rows][dst half: NB rows]; after k_hreduce the src half
    // holds per-block dst prefixes and the dst half is dead -> edge_src overlays it.
    unsigned int* hist = (unsigned int*)p;
    int* edge_src = (int*)(hist + (size_t)NB * NW);
    size_t dstHalf = (size_t)NB * NW * 4;
    size_t edgeBytes = (size_t)E * 4;
    p += align256((size_t)NB * NW * 4 + (edgeBytes > dstHalf ? edgeBytes : dstHalf));
    int* deg_in  = (int*)p;      p += align256((size_t)N * sizeof(int));
    int* offsets = (int*)p;      p += align256((size_t)(N + 1) * sizeof(int));
    int* partial = (int*)p;      p += align256((size_t)(nbh + 1) * sizeof(int));
    float* norm_out = (float*)p; p += align256((size_t)N * sizeof(float));
    float* norm_in  = (float*)p; p += align256((size_t)N * sizeof(float));
    float* beff  = (float*)p;    p += align256(128 * sizeof(float));
    unsigned short* xh  = (unsigned short*)p; p += align256((size_t)N * D * 2);
    unsigned short* yh  = (unsigned short*)p; p += align256((size_t)N * D * 2);
    unsigned short* Wt  = (unsigned short*)p; p += align256(256 * 128 * 2);

    k_stage1<<<nHist + nX4 + 33, 1024, 0, stream>>>(
        src, dst, hist, E, NW, nHist,
        x, xh, total4, nX4,
        Wconv, Waggr, bconv, baggr, Wt, beff);
    k_hreduce<<<nbh, 256, 0, stream>>>(hist, deg_in, norm_out, norm_in, partial, N, NW);
    k_scan3<<<nbh, 256, 0, stream>>>(deg_in, partial, offsets, N);
    k_scatter<<<dim3(NB, RS), 1024, 0, stream>>>(src, dst, offsets, hist, edge_src, E, NW);
    k_aggr<<<(N + 3) / 4, 256, 0, stream>>>(xh, edge_src, offsets, norm_out, norm_in, yh, N);
    k_gemm<<<(N + 63) / 64, 256, 0, stream>>>(yh, xh, Wt, beff, out, N);
}

// Round 8
// 197.520 us; speedup vs baseline: 1.4064x; 1.0294x over previous
//
#include <hip/hip_runtime.h>

#define D 128
#define NB 64              // histogram/scatter blocks per type
#define RBITS 15           // node-range split: 32768 bins per range
#define RSIZE (1 << RBITS)
#define RWORDS (RSIZE / 2) // 16384 packed words = 64 KB LDS

typedef short short8 __attribute__((ext_vector_type(8)));
typedef float f32x4 __attribute__((ext_vector_type(4)));

static __device__ __forceinline__ unsigned short f2bf(float f) {
    unsigned int u = __float_as_uint(f);
    unsigned int r = (u + 0x7FFFu + ((u >> 16) & 1u)) >> 16;
    return (unsigned short)r;
}
static __device__ __forceinline__ float bflo(unsigned int w) {
    return __uint_as_float(w << 16);
}
static __device__ __forceinline__ float bfhi(unsigned int w) {
    return __uint_as_float(w & 0xffff0000u);
}
static __device__ __forceinline__ unsigned int pk2bf(float lo, float hi) {
    return (unsigned int)f2bf(lo) | ((unsigned int)f2bf(hi) << 16);
}

// ---------------- S1: fused front-end: zone A = histograms, zone B = x->bf16,
//                     zone C = weight fold. All independent of each other. ----------------
__global__ __launch_bounds__(1024) void k_stage1(
    const int* __restrict__ src, const int* __restrict__ dst,
    unsigned int* __restrict__ hist, int E, int NW, int nHist,
    const float* __restrict__ x, unsigned short* __restrict__ xh, long long total4, int nX4,
    const float* __restrict__ Wc, const float* __restrict__ Wa,
    const float* __restrict__ bc, const float* __restrict__ ba,
    unsigned short* __restrict__ Wt, float* __restrict__ beff) {
    __shared__ unsigned int h[RWORDS];
    int t = threadIdx.x;
    int bx = blockIdx.x;

    if (bx < nHist) {
        // ---- zone A: per-block packed histograms (LDS atomics only) ----
        int b = bx % NB;
        int type = (bx / NB) & 1;
        int z = bx / (NB * 2);
        const int* __restrict__ ids = type ? dst : src;
        for (int i = t; i < RWORDS; i += 1024) h[i] = 0;
        __syncthreads();
        int slice = (E + NB - 1) / NB;
        int beg = b * slice;
        int end = beg + slice; if (end > E) end = E;
        for (int e = beg + t; e < end; e += 1024) {
            int v = ids[e];
            if ((v >> RBITS) != z) continue;
            int lv = v & (RSIZE - 1);
            atomicAdd(&h[lv >> 1], 1u << ((lv & 1) * 16));
        }
        __syncthreads();
        unsigned int* outp = hist + (size_t)(type * NB + b) * NW;
        int wbeg = z * RWORDS;
        int wend = wbeg + RWORDS; if (wend > NW) wend = NW;
        for (int i = wbeg + t; i < wend; i += 1024) outp[i] = h[i - wbeg];
    } else if (bx < nHist + nX4) {
        // ---- zone B: x -> bf16 (unscaled) ----
        long long i = (long long)(bx - nHist) * 1024 + t;
        if (i < total4) {
            float4 v = *(const float4*)&x[i * 4];
            ushort4 o;
            o.x = f2bf(v.x); o.y = f2bf(v.y); o.z = f2bf(v.z); o.w = f2bf(v.w);
            *(ushort4*)&xh[i * 4] = o;
        }
    } else {
        // ---- zone C: Wt[j*256+k] = k<128 ? (Wc@Wa_top)[k][j] : Wa[k][j]; beff ----
        int cidx = bx - nHist - nX4;
        if (cidx < 32) {
            int o = cidx * 1024 + t;
            int k = o >> 7;
            int j = o & 127;
            float acc;
            if (k < 128) {
                acc = 0.f;
                for (int l = 0; l < 128; l++) acc += Wc[k * 128 + l] * Wa[l * 128 + j];
            } else {
                acc = Wa[k * 128 + j];
            }
            Wt[(size_t)j * 256 + k] = f2bf(acc);
        } else if (t < 128) {
            float acc = ba[t];
            for (int k = 0; k < 128; k++) acc += bc[k] * Wa[k * 128 + t];
            beff[t] = acc;
        }
    }
}

// ---------------- S2: reduce hists -> deg/norms; rewrite src-hist as dst prefixes;
//                     emit per-block partial sums ----------------
__global__ __launch_bounds__(256) void k_hreduce(unsigned int* __restrict__ hist,
                                                 int* __restrict__ deg_in,
                                                 float* __restrict__ norm_out,
                                                 float* __restrict__ norm_in,
                                                 int* __restrict__ partial,
                                                 int N, int NW) {
    __shared__ int red[256];
    int t = threadIdx.x;
    int w = blockIdx.x * 256 + t;
    unsigned int p0 = 0, p1 = 0;
    if (w < NW) {
        unsigned int do0 = 0, do1 = 0;
        for (int b = 0; b < NB; b++) {
            unsigned int v = hist[(size_t)b * NW + w];
            do0 += v & 0xffffu; do1 += v >> 16;
        }
        for (int b = 0; b < NB; b++) {
            unsigned int v = hist[(size_t)(NB + b) * NW + w];
            hist[(size_t)b * NW + w] = p0 | (p1 << 16);  // thread-exclusive word: no race
            p0 += v & 0xffffu; p1 += v >> 16;
        }
        int n0 = 2 * w, n1 = 2 * w + 1;
        deg_in[n0]   = (int)p0;
        norm_out[n0] = rsqrtf((float)(do0 > 1 ? do0 : 1));
        norm_in[n0]  = rsqrtf((float)(p0 > 1 ? p0 : 1));
        if (n1 < N) {
            deg_in[n1]   = (int)p1;
            norm_out[n1] = rsqrtf((float)(do1 > 1 ? do1 : 1));
            norm_in[n1]  = rsqrtf((float)(p1 > 1 ? p1 : 1));
        } else {
            p1 = 0;
        }
    }
    red[t] = (int)(p0 + p1);
    __syncthreads();
    for (int off = 128; off > 0; off >>= 1) {
        if (t < off) red[t] += red[t + off];
        __syncthreads();
    }
    if (t == 0) partial[blockIdx.x] = red[0];
}

// ---------------- S3: scan with self-computed block prefix (512 nodes/block) ----------------
__global__ __launch_bounds__(256) void k_scan3(const int* __restrict__ deg,
                                               const int* __restrict__ partial,
                                               int* __restrict__ offsets, int N) {
    __shared__ int red[256];
    int t = threadIdx.x;
    int bx = blockIdx.x;
    // block prefix over partials (gridDim.x <= 256)
    int pv = (t < bx) ? partial[t] : 0;
    red[t] = pv;
    __syncthreads();
    for (int off = 128; off > 0; off >>= 1) {
        if (t < off) red[t] += red[t + off];
        __syncthreads();
    }
    int base = red[0];
    __syncthreads();

    int nb2 = bx * 512 + t * 2;
    int v0 = (nb2 < N) ? deg[nb2] : 0;
    int v1 = (nb2 + 1 < N) ? deg[nb2 + 1] : 0;
    int s = v0 + v1;
    red[t] = s;
    __syncthreads();
    for (int off = 1; off < 256; off <<= 1) {
        int a = (t >= off) ? red[t - off] : 0;
        __syncthreads();
        red[t] += a;
        __syncthreads();
    }
    int excl = red[t] - s + base;
    if (nb2 < N)     offsets[nb2] = excl;
    if (nb2 + 1 < N) offsets[nb2 + 1] = excl + v0;
    if (bx == gridDim.x - 1 && t == 255) offsets[N] = base + red[255];
}

// ---------------- S4: counting-sort scatter — no global atomics ----------------
__global__ __launch_bounds__(1024) void k_scatter(const int* __restrict__ src,
                                                  const int* __restrict__ dst,
                                                  const int* __restrict__ offsets,
                                                  const unsigned int* __restrict__ prefix,
                                                  int* __restrict__ edge_src,
                                                  int E, int NW) {
    __shared__ unsigned int h[RWORDS];
    int t = threadIdx.x;
    int b = blockIdx.x;
    int z = blockIdx.y;
    for (int i = t; i < RWORDS; i += 1024) h[i] = 0;
    __syncthreads();
    int slice = (E + NB - 1) / NB;
    int beg = b * slice;
    int end = beg + slice; if (end > E) end = E;
    const unsigned int* __restrict__ prow = prefix + (size_t)b * NW;
    for (int e = beg + t; e < end; e += 1024) {
        int d = dst[e];
        if ((d >> RBITS) != z) continue;
        int lv = d & (RSIZE - 1);
        int sh = (lv & 1) * 16;
        unsigned int old = atomicAdd(&h[lv >> 1], 1u << sh);
        int rank = (int)((old >> sh) & 0xffffu);
        int base = offsets[d] + (int)((prow[d >> 1] >> sh) & 0xffffu);
        edge_src[base + rank] = src[e];
    }
}

// ---------------- S5: CSR aggregation: full-wave rows, unroll-8 in flight ----------------
// one wave per node; each row read is one coalesced 256B transaction (4B/lane).
__global__ __launch_bounds__(256) void k_aggr(const unsigned short* __restrict__ xh,
                                              const int* __restrict__ edge_src,
                                              const int* __restrict__ offsets,
                                              const float* __restrict__ norm_out,
                                              const float* __restrict__ norm_in,
                                              unsigned short* __restrict__ yh, int N) {
    int node = blockIdx.x * 4 + (threadIdx.x >> 6);
    int lane = threadIdx.x & 63;
    if (node >= N) return;
    int beg = offsets[node];
    int end = offsets[node + 1];
    float nd = norm_in[node];
    float ax = 0.f, ay = 0.f;

    for (int jb = beg; jb < end; jb += 64) {
        int cnt = end - jb; if (cnt > 64) cnt = 64;
        int eidx = 0; float nsv = 0.f;
        if (lane < cnt) {
            eidx = edge_src[jb + lane];     // one coalesced batch load
            nsv  = norm_out[eidx];          // 64 gathers in flight
        }
        int k = 0;
        for (; k + 8 <= cnt; k += 8) {
#pragma unroll
            for (int u = 0; u < 8; u++) {   // 8 independent 256B row loads in flight
                int s = __shfl(eidx, k + u);
                float ns = __shfl(nsv, k + u);
                unsigned int v = *(const unsigned int*)&xh[(size_t)s * D + lane * 2];
                ax += bflo(v) * ns;
                ay += bfhi(v) * ns;
            }
        }
        for (; k < cnt; k++) {
            int s = __shfl(eidx, k);
            float ns = __shfl(nsv, k);
            unsigned int v = *(const unsigned int*)&xh[(size_t)s * D + lane * 2];
            ax += bflo(v) * ns;
            ay += bfhi(v) * ns;
        }
    }

    *(unsigned int*)&yh[(size_t)node * D + lane * 2] = pk2bf(ax * nd, ay * nd);
}

// ---------------- S6: MFMA GEMM: out = [yh | xh] @ W + beff ----------------
#define WT_STRIDE 136
__global__ __launch_bounds__(256) void k_gemm(const unsigned short* __restrict__ yh,
                                              const unsigned short* __restrict__ xh,
                                              const unsigned short* __restrict__ Wt,
                                              const float* __restrict__ beff,
                                              float* __restrict__ out, int N) {
    __shared__ unsigned short Bs[128 * WT_STRIDE];

    int t = threadIdx.x;
    int w = t >> 6;
    int lane = t & 63;
    int m = lane & 15;
    int q = lane >> 4;
    int row0 = blockIdx.x * 64;
    int arow = row0 + w * 16 + m;
    bool arow_ok = arow < N;

    f32x4 acc[8];
#pragma unroll
    for (int ct = 0; ct < 8; ct++) acc[ct] = (f32x4){0.f, 0.f, 0.f, 0.f};

    for (int kh = 0; kh < 2; kh++) {
#pragma unroll
        for (int i = 0; i < 8; i++) {
            int idx = t + i * 256;
            int rr = idx >> 4;
            int cc = (idx & 15) * 8;
            *(short8*)&Bs[rr * WT_STRIDE + cc] =
                *(const short8*)&Wt[(size_t)rr * 256 + kh * 128 + cc];
        }
        __syncthreads();

        const unsigned short* Abase = (kh == 0) ? yh : xh;
        const unsigned short* arowp = Abase + (size_t)arow * D;

#pragma unroll
        for (int kk = 0; kk < 4; kk++) {
            short8 a = (short8){0,0,0,0,0,0,0,0};
            if (arow_ok) a = *(const short8*)&arowp[kk * 32 + q * 8];
#pragma unroll
            for (int ct = 0; ct < 8; ct++) {
                short8 b = *(const short8*)&Bs[(ct * 16 + m) * WT_STRIDE + kk * 32 + q * 8];
                acc[ct] = __builtin_amdgcn_mfma_f32_16x16x32_bf16(a, b, acc[ct], 0, 0, 0);
            }
        }
        __syncthreads();
    }

#pragma unroll
    for (int ct = 0; ct < 8; ct++) {
        int col = ct * 16 + m;
        float bv = beff[col];
#pragma unroll
        for (int j = 0; j < 4; j++) {
            int r = row0 + w * 16 + q * 4 + j;
            if (r < N) out[(size_t)r * D + col] = acc[ct][j] + bv;
        }
    }
}

static size_t align256(size_t v) { return (v + 255) & ~(size_t)255; }

extern "C" void kernel_launch(void* const* d_in, const int* in_sizes, int n_in,
                              void* d_out, int out_size, void* d_ws, size_t ws_size,
                              hipStream_t stream) {
    const float* x     = (const float*)d_in[0];
    const int*   src   = (const int*)d_in[1];
    const int*   dst   = (const int*)d_in[2];
    const float* Wconv = (const float*)d_in[3];
    const float* bconv = (const float*)d_in[4];
    const float* Waggr = (const float*)d_in[5];
    const float* baggr = (const float*)d_in[6];
    float* out = (float*)d_out;

    int N = in_sizes[0] / D;
    int E = in_sizes[1];
    int NW = (N + 1) / 2;               // packed words per histogram row
    int RS = (N + RSIZE - 1) / RSIZE;   // node-range splits
    int nbh = (NW + 255) / 256;         // hreduce/scan blocks (512 nodes each)
    int nHist = NB * 2 * RS;
    long long total4 = (long long)N * D / 4;
    int nX4 = (int)((total4 + 1023) / 1024);

    char* p = (char*)d_ws;
    // hist: [src half: NB rows][dst half: NB rows]; after k_hreduce the src half
    // holds per-block dst prefixes and the dst half is dead -> edge_src overlays it.
    unsigned int* hist = (unsigned int*)p;
    int* edge_src = (int*)(hist + (size_t)NB * NW);
    size_t dstHalf = (size_t)NB * NW * 4;
    size_t edgeBytes = (size_t)E * 4;
    p += align256((size_t)NB * NW * 4 + (edgeBytes > dstHalf ? edgeBytes : dstHalf));
    int* deg_in  = (int*)p;      p += align256((size_t)N * sizeof(int));
    int* offsets = (int*)p;      p += align256((size_t)(N + 1) * sizeof(int));
    int* partial = (int*)p;      p += align256((size_t)(nbh + 1) * sizeof(int));
    float* norm_out = (float*)p; p += align256((size_t)N * sizeof(float));
    float* norm_in  = (float*)p; p += align256((size_t)N * sizeof(float));
    float* beff  = (float*)p;    p += align256(128 * sizeof(float));
    unsigned short* xh  = (unsigned short*)p; p += align256((size_t)N * D * 2);
    unsigned short* yh  = (unsigned short*)p; p += align256((size_t)N * D * 2);
    unsigned short* Wt  = (unsigned short*)p; p += align256(256 * 128 * 2);

    k_stage1<<<nHist + nX4 + 33, 1024, 0, stream>>>(
        src, dst, hist, E, NW, nHist,
        x, xh, total4, nX4,
        Wconv, Waggr, bconv, baggr, Wt, beff);
    k_hreduce<<<nbh, 256, 0, stream>>>(hist, deg_in, norm_out, norm_in, partial, N, NW);
    k_scan3<<<nbh, 256, 0, stream>>>(deg_in, partial, offsets, N);
    k_scatter<<<dim3(NB, RS), 1024, 0, stream>>>(src, dst, offsets, hist, edge_src, E, NW);
    k_aggr<<<(N + 3) / 4, 256, 0, stream>>>(xh, edge_src, offsets, norm_out, norm_in, yh, N);
    k_gemm<<<(N + 63) / 64, 256, 0, stream>>>(yh, xh, Wt, beff, out, N);
}